// Round 1
// baseline (172.556 us; speedup 1.0000x reference)
//
#include <hip/hip_runtime.h>
#include <math.h>

// ---------------------------------------------------------------------------
// Mann eddy-lifetime: tau = gamma * t^{-2/3} / sqrt(2F1(1/3,17/6,4/3,-t^-2))
// with t = L*||k||. Via Pfaff transform, 2F1 = (t^2 w)^{1/3} * s(w),
// w = 1/(1+t^2), s(w) = sum C_n w^n. Algebra collapses the output to
//   tau = rsqrt( t^2 * cbrt(w) * s(w) )
// Series coefficients C_n decay ~0.2*n^{-3.5}; NT=48 gives relative
// truncation ~8e-6 (tail ~ 0.08*N^-2.5), far inside the absmax threshold.
//
// This revision vs previous (155-157 us harness, kernel est. ~35 us):
//  - v_rcp_f32 (1 ulp) instead of exact-division sequence for w
//  - hw builtins for log2/exp2/rsq (no libm range-check wrappers)
//  - 8 points/thread (6x float4 = 96 B/lane): 2x MLP + 8 independent
//    Horner chains for latency hiding
//  - NT 64 -> 48 (shorter dependent FMA chain)
//  - nontemporal load/store hints (pure streaming, no reuse)
// ---------------------------------------------------------------------------

typedef float f4 __attribute__((ext_vector_type(4)));

constexpr int NT = 48;

struct CoefArr { float v[NT]; };

constexpr CoefArr gen_coefs() {
    CoefArr r{};
    double term = 1.0;
    r.v[0] = 1.0f;
    for (int n = 0; n + 1 < NT; ++n) {
        const double a  = 1.0 / 3.0;
        const double bp = -1.5;        // c - b = 4/3 - 17/6
        const double c  = 4.0 / 3.0;
        term *= ((a + n) * (bp + n)) / ((c + n) * (n + 1.0));
        r.v[n + 1] = (float)term;
    }
    return r;
}

constexpr CoefArr COEF = gen_coefs();   // folded to immediates at compile time

__device__ __forceinline__ float mann_tau(float t2) {
    // w in (0,1]; t2 == 0 handled by caller (masked to 0)
    float w = __builtin_amdgcn_rcpf(1.0f + t2);   // v_rcp_f32, ~1 ulp
    // Horner over compile-time constants
    float s = COEF.v[NT - 1];
#pragma unroll
    for (int n = NT - 2; n >= 0; --n) s = fmaf(s, w, COEF.v[n]);
    // cbrt(w) via hw log2/exp2 (w > 0 always)
    float cw = __builtin_amdgcn_exp2f(__builtin_amdgcn_logf(w) * (1.0f / 3.0f));
    return __builtin_amdgcn_rsqf(t2 * cw * s);    // v_rsq_f32
}

__global__ __launch_bounds__(256) void mann_elt_kernel(
    const float* __restrict__ k,
    const float* __restrict__ Lp,
    const float* __restrict__ gp,
    float* __restrict__ out,
    int n)               // n = number of output elements
{
    const int  gid  = blockIdx.x * blockDim.x + threadIdx.x;
    const long base = (long)gid * 8;
    if (base >= n) return;

    const float L  = Lp[0];
    const float g  = gp[0];
    const float L2 = L * L;

    if (base + 7 < (long)n) {
        // fast path: 8 points = 24 floats = 6 x float4, contiguous 96 B/lane
        const f4* k4 = (const f4*)k + (size_t)gid * 6;
        float f[24];
#pragma unroll
        for (int j = 0; j < 6; ++j) {
            f4 v = __builtin_nontemporal_load(&k4[j]);
            f[4 * j + 0] = v[0];
            f[4 * j + 1] = v[1];
            f[4 * j + 2] = v[2];
            f[4 * j + 3] = v[3];
        }

        float res[8];
#pragma unroll
        for (int j = 0; j < 8; ++j) {
            float x = f[3 * j + 0];
            float y = f[3 * j + 1];
            float z = f[3 * j + 2];
            float t2  = L2 * fmaf(x, x, fmaf(y, y, z * z));
            float tau = mann_tau(t2);
            res[j] = (t2 > 0.0f) ? g * tau : 0.0f;
        }

        f4 o0 = (f4){res[0], res[1], res[2], res[3]};
        f4 o1 = (f4){res[4], res[5], res[6], res[7]};
        f4* o4 = (f4*)(out + base);
        __builtin_nontemporal_store(o0, o4 + 0);
        __builtin_nontemporal_store(o1, o4 + 1);
    } else {
        // tail (n not divisible by 8) — scalar fallback
        for (int j = 0; j < 8 && base + j < (long)n; ++j) {
            const long i = base + j;
            float kx = k[3 * i + 0];
            float ky = k[3 * i + 1];
            float kz = k[3 * i + 2];
            float t2  = L2 * (kx * kx + ky * ky + kz * kz);
            float tau = mann_tau(t2);
            out[i] = (t2 > 0.0f) ? g * tau : 0.0f;
        }
    }
}

extern "C" void kernel_launch(void* const* d_in, const int* in_sizes, int n_in,
                              void* d_out, int out_size, void* d_ws, size_t ws_size,
                              hipStream_t stream) {
    const float* k  = (const float*)d_in[0];
    const float* L  = (const float*)d_in[1];
    const float* g  = (const float*)d_in[2];
    float* out = (float*)d_out;

    const int n  = out_size;            // 256*256*128 = 8388608
    const int n8 = (n + 7) / 8;         // threads, 8 elements each
    const int block = 256;
    const int grid  = (n8 + block - 1) / block;

    mann_elt_kernel<<<grid, block, 0, stream>>>(k, L, g, out, n);
}

// Round 2
// 155.202 us; speedup vs baseline: 1.1118x; 1.1118x over previous
//
#include <hip/hip_runtime.h>
#include <math.h>

// ---------------------------------------------------------------------------
// Mann eddy-lifetime: tau = gamma * t^{-2/3} / sqrt(2F1(1/3,17/6,4/3,-t^-2))
// with t = L*||k||. Via Pfaff transform, 2F1 = (t^2 w)^{1/3} * s(w),
// w = 1/(1+t^2), s(w) = sum C_n w^n. Algebra collapses the output to
//   tau = rsqrt( t^2 * cbrt(w) * s(w) )
// NT=48 series terms: truncation ~8e-6 rel., far inside absmax threshold.
//
// Round-2 structure: LDS-staged fully-coalesced loads.
//  - Each block: 1024 points = 3072 floats = 768 float4 = 12 KB LDS.
//  - Global->LDS: 3 float4 loads/thread at lane-consecutive addresses
//    (1 KiB per wave-instruction, ideal coalescing). This replaces the
//    per-lane 48/96-B chunk pattern of rounds 0/1, whose per-instruction
//    64-line footprint underachieved streaming BW (round-1 NT loads on
//    that pattern regressed 157->172 us by dropping partially-used lines).
//  - LDS->reg: 3 x float4 per thread, 48-B contiguous, 16-B aligned.
//  - Math: NT=48 Horner, v_rcp_f32, raw v_log/v_exp/v_rsq builtins.
//  - Store: 1 coalesced float4/thread, nontemporal (write-only stream).
// ---------------------------------------------------------------------------

typedef float f4 __attribute__((ext_vector_type(4)));

constexpr int NT = 48;

struct CoefArr { float v[NT]; };

constexpr CoefArr gen_coefs() {
    CoefArr r{};
    double term = 1.0;
    r.v[0] = 1.0f;
    for (int n = 0; n + 1 < NT; ++n) {
        const double a  = 1.0 / 3.0;
        const double bp = -1.5;        // c - b = 4/3 - 17/6
        const double c  = 4.0 / 3.0;
        term *= ((a + n) * (bp + n)) / ((c + n) * (n + 1.0));
        r.v[n + 1] = (float)term;
    }
    return r;
}

constexpr CoefArr COEF = gen_coefs();   // folded to immediates at compile time

__device__ __forceinline__ float mann_tau(float t2) {
    // w in (0,1]; t2 == 0 handled by caller (masked to 0)
    float w = __builtin_amdgcn_rcpf(1.0f + t2);   // v_rcp_f32, ~1 ulp
    float s = COEF.v[NT - 1];
#pragma unroll
    for (int n = NT - 2; n >= 0; --n) s = fmaf(s, w, COEF.v[n]);
    // cbrt(w) via hw log2/exp2 (w > 0 always)
    float cw = __builtin_amdgcn_exp2f(__builtin_amdgcn_logf(w) * (1.0f / 3.0f));
    return __builtin_amdgcn_rsqf(t2 * cw * s);    // v_rsq_f32
}

__global__ __launch_bounds__(256) void mann_elt_kernel(
    const float* __restrict__ k,
    const float* __restrict__ Lp,
    const float* __restrict__ gp,
    float* __restrict__ out,
    int n)               // n = number of output elements (points)
{
    const int  t        = threadIdx.x;
    const long blockPts = (long)blockIdx.x * 1024;   // points per block

    const float L  = Lp[0];
    const float g  = gp[0];
    const float L2 = L * L;

    __shared__ f4 sk4[768];                          // 12 KB

    if (blockPts + 1024 <= (long)n) {
        // ---- fast path: full block, fully coalesced staging ----
        const f4* kg    = (const f4*)k;
        const long base4 = blockPts * 3 / 4;         // = blockIdx.x * 768
#pragma unroll
        for (int i = 0; i < 3; ++i)
            sk4[t + i * 256] = kg[base4 + t + i * 256];
        __syncthreads();

        // this thread's 4 points: floats [t*12, t*12+12) in the block tile
        const float* skf = (const float*)sk4;
        const f4*    sp  = (const f4*)(skf + t * 12); // 48-B, 16-B aligned
        f4 p0 = sp[0];
        f4 p1 = sp[1];
        f4 p2 = sp[2];

        float n2[4];
        n2[0] = fmaf(p0[0], p0[0], fmaf(p0[1], p0[1], p0[2] * p0[2]));
        n2[1] = fmaf(p0[3], p0[3], fmaf(p1[0], p1[0], p1[1] * p1[1]));
        n2[2] = fmaf(p1[2], p1[2], fmaf(p1[3], p1[3], p2[0] * p2[0]));
        n2[3] = fmaf(p2[1], p2[1], fmaf(p2[2], p2[2], p2[3] * p2[3]));

        f4 o;
#pragma unroll
        for (int j = 0; j < 4; ++j) {
            float t2  = L2 * n2[j];
            float tau = mann_tau(t2);
            o[j] = (t2 > 0.0f) ? g * tau : 0.0f;
        }
        // coalesced 16-B/lane store; write-only stream -> nontemporal
        __builtin_nontemporal_store(o, (f4*)(out + blockPts) + t);
    } else {
        // ---- tail block (n not divisible by 1024) — scalar fallback ----
        for (int j = 0; j < 4; ++j) {
            const long i = blockPts + (long)t * 4 + j;
            if (i >= (long)n) break;
            float kx = k[3 * i + 0];
            float ky = k[3 * i + 1];
            float kz = k[3 * i + 2];
            float t2  = L2 * (kx * kx + ky * ky + kz * kz);
            float tau = mann_tau(t2);
            out[i] = (t2 > 0.0f) ? g * tau : 0.0f;
        }
    }
}

extern "C" void kernel_launch(void* const* d_in, const int* in_sizes, int n_in,
                              void* d_out, int out_size, void* d_ws, size_t ws_size,
                              hipStream_t stream) {
    const float* k  = (const float*)d_in[0];
    const float* L  = (const float*)d_in[1];
    const float* g  = (const float*)d_in[2];
    float* out = (float*)d_out;

    const int n = out_size;                 // 256*256*128 = 8388608 points
    const int block = 256;
    const int ptsPerBlock = 1024;           // 4 points/thread
    const int grid = (n + ptsPerBlock - 1) / ptsPerBlock;   // 8192 exactly

    mann_elt_kernel<<<grid, block, 0, stream>>>(k, L, g, out, n);
}